// Round 2
// baseline (522.574 us; speedup 1.0000x reference)
//
#include <hip/hip_runtime.h>

// ClusteringLoss on MI355X — fused streaming stencil + reduction, round 2.
// B=8, K=8, H=W=1024. Memory-bound: ~324 MiB read (12.5% halo) -> ~54 us floor.
// R2: full row-loop unroll (MLP), no memset / no atomics (per-block slots).

constexpr int Bsz  = 8;
constexpr int Kc   = 8;
constexpr int H    = 1024;
constexpr int W    = 1024;
constexpr int ROWS = 8;          // rows per block; halo overhead = 1/ROWS
constexpr int RB   = H / ROWS;   // 128 row-blocks per image
constexpr int TPB  = 256;        // thread covers 4 cols (float4); 256*4 = W

#define GAMMA_F    10.0f
#define EPS_SQRT_F 1e-24f

__device__ __forceinline__ float wedge(float c, float dn, float rt,
                                       float inv_sx, float inv_sy, float smin) {
    float dx = (dn - c) * inv_sx;
    float dy = (rt - c) * inv_sy;
    float gn2 = dx * dx + dy * dy;
    float g = sqrtf(fmaxf(gn2, EPS_SQRT_F));
    return 1.0f / (1.0f + GAMMA_F * g * smin);
}

__device__ __forceinline__ void accum(float pc, float pd, float pr, float w,
                                      float& nom, float& den) {
    float lap = (pd - pc) + (pr - pc);          // p_xp + p_yp
    nom = fmaf(pc, fmaf(w, lap, pc), nom);      // pc*(pc + w*lap)
    den = fmaf(pc, fmaf(2.0f, w, 1.0f), den);   // pc*(1 + 2w)
}

__global__ __launch_bounds__(TPB, 4) void cl_main(const float* __restrict__ I,
                                                  const float* __restrict__ spacing,
                                                  const float* __restrict__ P,
                                                  float2* __restrict__ ws) {
    const int t  = threadIdx.x;
    const int j0 = t * 4;
    const int b  = blockIdx.y;
    const int r0 = blockIdx.x * ROWS;

    const float sx = spacing[0], sy = spacing[1];
    const float inv_sx = 1.0f / sx, inv_sy = 1.0f / sy;
    const float smin = fminf(sx, sy);

    const int jr = (j0 + 4 < W) ? (j0 + 4) : (W - 1);  // right halo col (clamped)

    const float* Ib = I + (size_t)b * H * W;
    const float* Pb = P + (size_t)b * Kc * H * W;

    // register carry: current row of I and all K channels of p
    float4 cI  = *(const float4*)(Ib + (size_t)r0 * W + j0);
    float  cIr = Ib[(size_t)r0 * W + jr];
    float4 cp[Kc];
    float  cpr[Kc];
#pragma unroll
    for (int k = 0; k < Kc; ++k) {
        const float* Pk = Pb + (size_t)k * H * W;
        cp[k]  = *(const float4*)(Pk + (size_t)r0 * W + j0);
        cpr[k] = Pk[(size_t)r0 * W + jr];
    }

    float nom[Kc], den[Kc];
#pragma unroll
    for (int k = 0; k < Kc; ++k) { nom[k] = 0.0f; den[k] = 0.0f; }

#pragma unroll
    for (int ii = 0; ii < ROWS; ++ii) {
        const int i = r0 + ii;
        const int inext = (i + 1 < H) ? (i + 1) : (H - 1);
        const float4 nI  = *(const float4*)(Ib + (size_t)inext * W + j0);
        const float  nIr = Ib[(size_t)inext * W + jr];

        const float w0 = wedge(cI.x, nI.x, cI.y, inv_sx, inv_sy, smin);
        const float w1 = wedge(cI.y, nI.y, cI.z, inv_sx, inv_sy, smin);
        const float w2 = wedge(cI.z, nI.z, cI.w, inv_sx, inv_sy, smin);
        const float w3 = wedge(cI.w, nI.w, cIr,  inv_sx, inv_sy, smin);

#pragma unroll
        for (int k = 0; k < Kc; ++k) {
            const float* Pk = Pb + (size_t)k * H * W;
            const float4 np  = *(const float4*)(Pk + (size_t)inext * W + j0);
            const float  npr = Pk[(size_t)inext * W + jr];

            accum(cp[k].x, np.x, cp[k].y, w0, nom[k], den[k]);
            accum(cp[k].y, np.y, cp[k].z, w1, nom[k], den[k]);
            accum(cp[k].z, np.z, cp[k].w, w2, nom[k], den[k]);
            accum(cp[k].w, np.w, cpr[k],  w3, nom[k], den[k]);

            cp[k]  = np;
            cpr[k] = npr;
        }
        cI  = nI;
        cIr = nIr;
    }

    // reduction: wave shuffle -> LDS -> per-block slot write (no atomics, no init)
    __shared__ float red[4][2 * Kc];
    const int lane = t & 63;
    const int wave = t >> 6;

#pragma unroll
    for (int k = 0; k < Kc; ++k) {
        float n = nom[k], d = den[k];
#pragma unroll
        for (int off = 32; off > 0; off >>= 1) {
            n += __shfl_down(n, off, 64);
            d += __shfl_down(d, off, 64);
        }
        if (lane == 0) {
            red[wave][k]      = n;
            red[wave][Kc + k] = d;
        }
    }
    __syncthreads();

    if (t < Kc) {
        const int k = t;
        float n = red[0][k] + red[1][k] + red[2][k] + red[3][k];
        float d = red[0][Kc + k] + red[1][Kc + k] + red[2][Kc + k] + red[3][Kc + k];
        ws[((size_t)(b * RB + blockIdx.x)) * Kc + k] = make_float2(n, d);
    }
}

__global__ void cl_final(const float2* __restrict__ ws, float* __restrict__ out) {
    const int t = threadIdx.x;  // 64 threads: (b = t>>3, k = t&7)
    const int b = t >> 3, k = t & 7;
    double n = 0.0, d = 0.0;
    for (int r = 0; r < RB; ++r) {
        const float2 v = ws[((size_t)(b * RB + r)) * Kc + k];
        n += (double)v.x;
        d += (double)v.y;
    }
    double c = n / d;
#pragma unroll
    for (int off = 32; off > 0; off >>= 1) c += __shfl_down(c, off, 64);
    if (t == 0) out[0] = (float)((double)(Bsz * Kc) - c);
}

extern "C" void kernel_launch(void* const* d_in, const int* in_sizes, int n_in,
                              void* d_out, int out_size, void* d_ws, size_t ws_size,
                              hipStream_t stream) {
    const float* I       = (const float*)d_in[0];  // (8,1,1024,1024)
    const float* spacing = (const float*)d_in[1];  // (2,)
    const float* P       = (const float*)d_in[2];  // (8,8,1024,1024)
    float* out = (float*)d_out;
    float2* ws = (float2*)d_ws;  // 8*128*8 float2 slots = 64 KiB, all overwritten

    dim3 grid(RB, Bsz);
    cl_main<<<grid, TPB, 0, stream>>>(I, spacing, P, ws);
    cl_final<<<1, 64, 0, stream>>>(ws, out);
}

// Round 3
// 419.431 us; speedup vs baseline: 1.2459x; 1.2459x over previous
//
#include <hip/hip_runtime.h>

// ClusteringLoss on MI355X — round 3.
// R2 failure: register-carry of 8 channels + launch_bounds(256,4) -> 64 VGPRs
// -> 282 MB scratch spill (WRITE_SIZE). R3: carry nothing; re-load cur+next
// rows each iter (2nd read is L1/L2 hit, HBM unchanged), minimal live state.

constexpr int Bsz  = 8;
constexpr int Kc   = 8;
constexpr int H    = 1024;
constexpr int W    = 1024;
constexpr int ROWS = 8;          // rows per block; halo overhead = 1/ROWS
constexpr int RB   = H / ROWS;   // 128 row-blocks per image
constexpr int TPB  = 256;        // thread covers 4 cols (float4); 256*4 = W

#define GAMMA_F    10.0f
#define EPS_SQRT_F 1e-24f

__device__ __forceinline__ float wedge(float c, float dn, float rt,
                                       float inv_sx, float inv_sy, float smin) {
    float dx = (dn - c) * inv_sx;
    float dy = (rt - c) * inv_sy;
    float gn2 = dx * dx + dy * dy;
    float g = sqrtf(fmaxf(gn2, EPS_SQRT_F));
    return 1.0f / (1.0f + GAMMA_F * g * smin);
}

__device__ __forceinline__ void accum(float pc, float pd, float pr, float w,
                                      float& nom, float& den) {
    float lap = (pd - pc) + (pr - pc);          // p_xp + p_yp
    nom = fmaf(pc, fmaf(w, lap, pc), nom);      // pc*(pc + w*lap)
    den = fmaf(pc, fmaf(2.0f, w, 1.0f), den);   // pc*(1 + 2w)
}

__global__ __launch_bounds__(TPB) void cl_main(const float* __restrict__ I,
                                               const float* __restrict__ spacing,
                                               const float* __restrict__ P,
                                               float2* __restrict__ ws) {
    const int t  = threadIdx.x;
    const int j0 = t * 4;
    const int b  = blockIdx.y;
    const int r0 = blockIdx.x * ROWS;

    const float sx = spacing[0], sy = spacing[1];
    const float inv_sx = 1.0f / sx, inv_sy = 1.0f / sy;
    const float smin = fminf(sx, sy);

    const int jr = (j0 + 4 < W) ? (j0 + 4) : (W - 1);  // right halo col (clamped)

    const float* Ib = I + (size_t)b * H * W;
    const float* Pb = P + (size_t)b * Kc * H * W;

    float nom[Kc], den[Kc];
#pragma unroll
    for (int k = 0; k < Kc; ++k) { nom[k] = 0.0f; den[k] = 0.0f; }

#pragma unroll 2
    for (int ii = 0; ii < ROWS; ++ii) {
        const int i = r0 + ii;
        const int inext = (i + 1 < H) ? (i + 1) : (H - 1);
        const size_t rc = (size_t)i * W;       // current-row offset
        const size_t rn = (size_t)inext * W;   // next-row offset

        const float4 cI  = *(const float4*)(Ib + rc + j0);
        const float4 nI  = *(const float4*)(Ib + rn + j0);
        const float  cIr = Ib[rc + jr];

        const float w0 = wedge(cI.x, nI.x, cI.y, inv_sx, inv_sy, smin);
        const float w1 = wedge(cI.y, nI.y, cI.z, inv_sx, inv_sy, smin);
        const float w2 = wedge(cI.z, nI.z, cI.w, inv_sx, inv_sy, smin);
        const float w3 = wedge(cI.w, nI.w, cIr,  inv_sx, inv_sy, smin);

#pragma unroll
        for (int k = 0; k < Kc; ++k) {
            const float* Pk = Pb + (size_t)k * H * W;
            const float4 cp  = *(const float4*)(Pk + rc + j0);
            const float4 np  = *(const float4*)(Pk + rn + j0);
            const float  cpr = Pk[rc + jr];

            accum(cp.x, np.x, cp.y, w0, nom[k], den[k]);
            accum(cp.y, np.y, cp.z, w1, nom[k], den[k]);
            accum(cp.z, np.z, cp.w, w2, nom[k], den[k]);
            accum(cp.w, np.w, cpr,  w3, nom[k], den[k]);
        }
    }

    // reduction: wave shuffle -> LDS -> per-block slot write (no atomics, no init)
    __shared__ float red[4][2 * Kc];
    const int lane = t & 63;
    const int wave = t >> 6;

#pragma unroll
    for (int k = 0; k < Kc; ++k) {
        float n = nom[k], d = den[k];
#pragma unroll
        for (int off = 32; off > 0; off >>= 1) {
            n += __shfl_down(n, off, 64);
            d += __shfl_down(d, off, 64);
        }
        if (lane == 0) {
            red[wave][k]      = n;
            red[wave][Kc + k] = d;
        }
    }
    __syncthreads();

    if (t < Kc) {
        const int k = t;
        float n = red[0][k] + red[1][k] + red[2][k] + red[3][k];
        float d = red[0][Kc + k] + red[1][Kc + k] + red[2][Kc + k] + red[3][Kc + k];
        ws[((size_t)(b * RB + blockIdx.x)) * Kc + k] = make_float2(n, d);
    }
}

// 512 threads: 8 threads per (b,k) accumulator, each strides 16 of 128 slots.
__global__ __launch_bounds__(512) void cl_final(const float2* __restrict__ ws,
                                                float* __restrict__ out) {
    const int t    = threadIdx.x;
    const int acc  = t & 63;        // (b = acc>>3, k = acc&7)
    const int part = t >> 6;        // 0..7
    const int b = acc >> 3, k = acc & 7;

    double n = 0.0, d = 0.0;
#pragma unroll
    for (int r = part; r < RB; r += 8) {
        const float2 v = ws[((size_t)(b * RB + r)) * Kc + k];
        n += (double)v.x;
        d += (double)v.y;
    }

    __shared__ double sn[64][8], sd[64][8];
    sn[acc][part] = n;
    sd[acc][part] = d;
    __syncthreads();

    if (t < 64) {
        double nn = 0.0, dd = 0.0;
#pragma unroll
        for (int p = 0; p < 8; ++p) { nn += sn[t][p]; dd += sd[t][p]; }
        double c = nn / dd;
#pragma unroll
        for (int off = 32; off > 0; off >>= 1) c += __shfl_down(c, off, 64);
        if (t == 0) out[0] = (float)((double)(Bsz * Kc) - c);
    }
}

extern "C" void kernel_launch(void* const* d_in, const int* in_sizes, int n_in,
                              void* d_out, int out_size, void* d_ws, size_t ws_size,
                              hipStream_t stream) {
    const float* I       = (const float*)d_in[0];  // (8,1,1024,1024)
    const float* spacing = (const float*)d_in[1];  // (2,)
    const float* P       = (const float*)d_in[2];  // (8,8,1024,1024)
    float* out = (float*)d_out;
    float2* ws = (float2*)d_ws;  // 8*128*8 float2 slots = 64 KiB, all overwritten

    dim3 grid(RB, Bsz);
    cl_main<<<grid, TPB, 0, stream>>>(I, spacing, P, ws);
    cl_final<<<1, 512, 0, stream>>>(ws, out);
}

// Round 4
// 385.182 us; speedup vs baseline: 1.3567x; 1.0889x over previous
//
#include <hip/hip_runtime.h>

// ClusteringLoss on MI355X — round 4.
// R3 reload design re-missed L2 (working set > 4MiB/XCD) -> slower than R1
// carry. R4: carry rows in registers but split K across blocks (4 ch/block)
// so carry state (~25 regs) can't spill; ROWS=16 (6.25% halo); right-halo
// neighbors via __shfl_down (lane63 predicated 1-lane load) instead of
// 64-lane stride-16B gathers. Traffic ~340 MiB -> ~56 us BW floor.

constexpr int Bsz  = 8;
constexpr int Kc   = 8;
constexpr int KPB  = 4;          // channels per block (K split in 2)
constexpr int H    = 1024;
constexpr int W    = 1024;
constexpr int ROWS = 16;         // rows per block; halo overhead = 1/ROWS
constexpr int RB   = H / ROWS;   // 64 row-blocks per image
constexpr int TPB  = 256;        // thread covers 4 cols (float4); 256*4 = W

#define GAMMA_F    10.0f
#define EPS_SQRT_F 1e-24f

__device__ __forceinline__ float wedge(float c, float dn, float rt,
                                       float inv_sx, float inv_sy, float smin) {
    float dx = (dn - c) * inv_sx;
    float dy = (rt - c) * inv_sy;
    float gn2 = dx * dx + dy * dy;
    float g = sqrtf(fmaxf(gn2, EPS_SQRT_F));
    return 1.0f / (1.0f + GAMMA_F * g * smin);
}

__device__ __forceinline__ void accum(float pc, float pd, float pr, float w,
                                      float& nom, float& den) {
    float lap = (pd - pc) + (pr - pc);          // p_xp + p_yp
    nom = fmaf(pc, fmaf(w, lap, pc), nom);      // pc*(pc + w*lap)
    den = fmaf(pc, fmaf(2.0f, w, 1.0f), den);   // pc*(1 + 2w)
}

__global__ __launch_bounds__(TPB) void cl_main(const float* __restrict__ I,
                                               const float* __restrict__ spacing,
                                               const float* __restrict__ P,
                                               float2* __restrict__ ws) {
    const int t    = threadIdx.x;
    const int lane = t & 63;
    const int j0   = t * 4;
    const int b    = blockIdx.y;
    const int kh   = blockIdx.z;             // K half: channels kh*4 .. kh*4+3
    const int r0   = blockIdx.x * ROWS;

    const float sx = spacing[0], sy = spacing[1];
    const float inv_sx = 1.0f / sx, inv_sy = 1.0f / sy;
    const float smin = fminf(sx, sy);

    const int jr = (j0 + 4 < W) ? (j0 + 4) : (W - 1);  // lane-63 halo col
    const bool edge = (lane == 63);

    const float* Ib = I + (size_t)b * H * W;
    const float* Pk0 = P + ((size_t)(b * Kc + kh * KPB)) * H * W;

    // ---- register carry: current row of I and 4 channels of p ----
    float4 cI  = *(const float4*)(Ib + (size_t)r0 * W + j0);
    float  cIr = edge ? Ib[(size_t)r0 * W + jr] : 0.0f;
    float4 cp[KPB];
    float  cpr[KPB];
#pragma unroll
    for (int k = 0; k < KPB; ++k) {
        const float* Pk = Pk0 + (size_t)k * H * W;
        cp[k]  = *(const float4*)(Pk + (size_t)r0 * W + j0);
        cpr[k] = edge ? Pk[(size_t)r0 * W + jr] : 0.0f;
    }

    float nom[KPB], den[KPB];
#pragma unroll
    for (int k = 0; k < KPB; ++k) { nom[k] = 0.0f; den[k] = 0.0f; }

#pragma unroll 1
    for (int ii = 0; ii < ROWS; ++ii) {
        const int i = r0 + ii;
        const int inext = (i + 1 < H) ? (i + 1) : (H - 1);
        const size_t rn = (size_t)inext * W;

        const float4 nI  = *(const float4*)(Ib + rn + j0);
        const float  nIr = edge ? Ib[rn + jr] : 0.0f;

        // right neighbor of cI.w: next lane's cI.x; lane 63 uses carried halo
        float Irt = __shfl_down(cI.x, 1, 64);
        if (edge) Irt = cIr;

        const float w0 = wedge(cI.x, nI.x, cI.y, inv_sx, inv_sy, smin);
        const float w1 = wedge(cI.y, nI.y, cI.z, inv_sx, inv_sy, smin);
        const float w2 = wedge(cI.z, nI.z, cI.w, inv_sx, inv_sy, smin);
        const float w3 = wedge(cI.w, nI.w, Irt,  inv_sx, inv_sy, smin);

#pragma unroll
        for (int k = 0; k < KPB; ++k) {
            const float* Pk = Pk0 + (size_t)k * H * W;
            const float4 np  = *(const float4*)(Pk + rn + j0);
            const float  npr = edge ? Pk[rn + jr] : 0.0f;

            float prt = __shfl_down(cp[k].x, 1, 64);
            if (edge) prt = cpr[k];

            accum(cp[k].x, np.x, cp[k].y, w0, nom[k], den[k]);
            accum(cp[k].y, np.y, cp[k].z, w1, nom[k], den[k]);
            accum(cp[k].z, np.z, cp[k].w, w2, nom[k], den[k]);
            accum(cp[k].w, np.w, prt,     w3, nom[k], den[k]);

            cp[k]  = np;
            cpr[k] = npr;
        }
        cI  = nI;
        cIr = nIr;
    }

    // ---- reduction: wave shuffle -> LDS -> per-block slot write ----
    __shared__ float red[4][2 * KPB];
    const int wave = t >> 6;

#pragma unroll
    for (int k = 0; k < KPB; ++k) {
        float n = nom[k], d = den[k];
#pragma unroll
        for (int off = 32; off > 0; off >>= 1) {
            n += __shfl_down(n, off, 64);
            d += __shfl_down(d, off, 64);
        }
        if (lane == 0) {
            red[wave][k]       = n;
            red[wave][KPB + k] = d;
        }
    }
    __syncthreads();

    if (t < KPB) {
        const int k = t;
        float n = red[0][k] + red[1][k] + red[2][k] + red[3][k];
        float d = red[0][KPB + k] + red[1][KPB + k] + red[2][KPB + k] + red[3][KPB + k];
        // slot layout: (((b*2 + kh)*RB + rowblock)*KPB + k)
        ws[(((size_t)(b * 2 + kh) * RB) + blockIdx.x) * KPB + k] = make_float2(n, d);
    }
}

// 512 threads: 8 partial-summers per (b,k) accumulator over 64 row-blocks.
__global__ __launch_bounds__(512) void cl_final(const float2* __restrict__ ws,
                                                float* __restrict__ out) {
    const int t    = threadIdx.x;
    const int acc  = t & 63;        // b = acc>>3, k = acc&7
    const int part = t >> 6;        // 0..7
    const int b = acc >> 3, k = acc & 7;
    const int kh = k >> 2, kk = k & 3;

    double n = 0.0, d = 0.0;
#pragma unroll
    for (int r = part; r < RB; r += 8) {
        const float2 v = ws[(((size_t)(b * 2 + kh) * RB) + r) * KPB + kk];
        n += (double)v.x;
        d += (double)v.y;
    }

    __shared__ double sn[64][8], sd[64][8];
    sn[acc][part] = n;
    sd[acc][part] = d;
    __syncthreads();

    if (t < 64) {
        double nn = 0.0, dd = 0.0;
#pragma unroll
        for (int p = 0; p < 8; ++p) { nn += sn[t][p]; dd += sd[t][p]; }
        double c = nn / dd;
#pragma unroll
        for (int off = 32; off > 0; off >>= 1) c += __shfl_down(c, off, 64);
        if (t == 0) out[0] = (float)((double)(Bsz * Kc) - c);
    }
}

extern "C" void kernel_launch(void* const* d_in, const int* in_sizes, int n_in,
                              void* d_out, int out_size, void* d_ws, size_t ws_size,
                              hipStream_t stream) {
    const float* I       = (const float*)d_in[0];  // (8,1,1024,1024)
    const float* spacing = (const float*)d_in[1];  // (2,)
    const float* P       = (const float*)d_in[2];  // (8,8,1024,1024)
    float* out = (float*)d_out;
    float2* ws = (float2*)d_ws;  // 8*2*64*4 float2 slots = 32 KiB, all overwritten

    dim3 grid(RB, Bsz, 2);
    cl_main<<<grid, TPB, 0, stream>>>(I, spacing, P, ws);
    cl_final<<<1, 512, 0, stream>>>(ws, out);
}